// Round 1
// baseline (2302.266 us; speedup 1.0000x reference)
//
#include <hip/hip_runtime.h>

typedef unsigned short UST;
typedef __bf16 v8bf __attribute__((ext_vector_type(8)));
typedef float  v4f  __attribute__((ext_vector_type(4)));

__device__ __forceinline__ UST f2b(float f) {
  union { float f; unsigned u; } x; x.f = f;
  unsigned u = x.u;
  unsigned r = (u + 0x7fffu + ((u >> 16) & 1u)) >> 16;
  return (UST)r;
}

// ---------------- x -> bf16 ----------------
__global__ __launch_bounds__(256) void k_convert(const float* __restrict__ src,
                                                 UST* __restrict__ dst, int n) {
  int i = (blockIdx.x * 256 + threadIdx.x) * 4;
  if (i >= n) return;
  float4 v = *(const float4*)(src + i);
  ushort4 o;
  o.x = f2b(v.x); o.y = f2b(v.y); o.z = f2b(v.z); o.w = f2b(v.w);
  *(ushort4*)(dst + i) = o;
}

// ---------------- W (RxC) -> WT (CxR) bf16 ----------------
__global__ __launch_bounds__(256) void k_transpose(const float* __restrict__ W,
                                                   UST* __restrict__ WT, int R, int C) {
  __shared__ float tile[32][33];
  int tx = threadIdx.x, ty = threadIdx.y;
  int r0 = blockIdx.y * 32, c0 = blockIdx.x * 32;
  for (int i = ty; i < 32; i += 8)
    tile[i][tx] = W[(size_t)(r0 + i) * C + c0 + tx];
  __syncthreads();
  for (int i = ty; i < 32; i += 8)
    WT[(size_t)(c0 + i) * R + r0 + tx] = f2b(tile[tx][i]);
}

// ---------------- GEMM: C[M,N] = A[M,K] @ BT[N,K]^T + bias ----------------
// mode 1: out bf16 head layout (B,N,T,D);  mode 2: out bf16 (B,N,D,T);  mode 3: fp32 plain
__global__ __launch_bounds__(256) void k_gemm_bt(const UST* __restrict__ A,
                                                 const UST* __restrict__ BT,
                                                 const float* __restrict__ bias,
                                                 int M, int N, int K, int mode,
                                                 void* __restrict__ outp) {
  __shared__ UST As[128 * 32];
  __shared__ UST Bs[128 * 32];
  int tid = threadIdx.x;
  int l = tid & 63, w = tid >> 6;
  int g = l >> 4, c16 = l & 15;
  int wm = w >> 1, wn = w & 1;
  int bm = blockIdx.y * 128, bn = blockIdx.x * 128;

  v4f acc[4][4];
  for (int i = 0; i < 4; i++)
    for (int j = 0; j < 4; j++)
      acc[i][j] = (v4f){0.f, 0.f, 0.f, 0.f};

  for (int kb = 0; kb < K; kb += 32) {
    int ch0 = tid, ch1 = tid + 256;
    uint4 a0 = *(const uint4*)(A + (size_t)(bm + (ch0 >> 2)) * K + kb + (ch0 & 3) * 8);
    uint4 a1 = *(const uint4*)(A + (size_t)(bm + (ch1 >> 2)) * K + kb + (ch1 & 3) * 8);
    uint4 b0 = *(const uint4*)(BT + (size_t)(bn + (ch0 >> 2)) * K + kb + (ch0 & 3) * 8);
    uint4 b1 = *(const uint4*)(BT + (size_t)(bn + (ch1 >> 2)) * K + kb + (ch1 & 3) * 8);
    __syncthreads();
    *(uint4*)(As + (size_t)ch0 * 8) = a0;
    *(uint4*)(As + (size_t)ch1 * 8) = a1;
    *(uint4*)(Bs + (size_t)ch0 * 8) = b0;
    *(uint4*)(Bs + (size_t)ch1 * 8) = b1;
    __syncthreads();

    v8bf af[4], bf[4];
    for (int mt = 0; mt < 4; mt++)
      af[mt] = *(const v8bf*)(As + (wm * 64 + mt * 16 + c16) * 32 + g * 8);
    for (int nt = 0; nt < 4; nt++)
      bf[nt] = *(const v8bf*)(Bs + (wn * 64 + nt * 16 + c16) * 32 + g * 8);
    for (int mt = 0; mt < 4; mt++)
      for (int nt = 0; nt < 4; nt++)
        acc[mt][nt] = __builtin_amdgcn_mfma_f32_16x16x32_bf16(af[mt], bf[nt], acc[mt][nt], 0, 0, 0);
  }

  for (int mt = 0; mt < 4; mt++)
    for (int nt = 0; nt < 4; nt++)
      for (int r = 0; r < 4; r++) {
        int row = bm + wm * 64 + mt * 16 + g * 4 + r;
        int col = bn + wn * 64 + nt * 16 + c16;
        float v = acc[mt][nt][r] + bias[col];
        if (mode == 1) {
          int b = row >> 11, t = row & 2047, hn = col >> 6, d = col & 63;
          ((UST*)outp)[((size_t)((b * 16 + hn) * 2048 + t)) * 64 + d] = f2b(v);
        } else if (mode == 2) {
          int b = row >> 11, t = row & 2047, hn = col >> 6, d = col & 63;
          ((UST*)outp)[((size_t)((b * 16 + hn) * 64 + d)) * 2048 + t] = f2b(v);
        } else {
          ((float*)outp)[(size_t)row * N + col] = v;
        }
      }
}

// ---------------- attention: per (qt, head, batch) block of 64 q-rows ----------------
__global__ __launch_bounds__(256) void k_attn(const UST* __restrict__ qh,
                                              const UST* __restrict__ kh,
                                              const UST* __restrict__ vT,
                                              float* __restrict__ Pout,
                                              UST* __restrict__ oh) {
  __shared__ UST Qs[64 * 64];
  __shared__ UST Ks[64 * 64];
  __shared__ UST Pt[4][16 * 32];

  int tid = threadIdx.x;
  int l = tid & 63, w = tid >> 6, g = l >> 4, c16 = l & 15;
  int qt = blockIdx.x, hn = blockIdx.y, b = blockIdx.z;

  const UST* qbase = qh + ((size_t)((b * 16 + hn) * 2048 + qt * 64)) * 64;
  const UST* kbase = kh + ((size_t)((b * 16 + hn) * 2048)) * 64;
  const UST* vbase = vT + ((size_t)((b * 16 + hn) * 64)) * 2048;
  float* pbase = Pout + ((size_t)((b * 16 + hn) * 2048 + qt * 64)) * 2048;

  // stage Q tile (64x64)
  {
    uint4 t0 = *(const uint4*)(qbase + (size_t)tid * 8);
    uint4 t1 = *(const uint4*)(qbase + (size_t)(tid + 256) * 8);
    *(uint4*)(Qs + (size_t)tid * 8) = t0;
    *(uint4*)(Qs + (size_t)(tid + 256) * 8) = t1;
  }
  __syncthreads();
  v8bf aq0 = *(const v8bf*)(Qs + (w * 16 + c16) * 64 + g * 8);
  v8bf aq1 = *(const v8bf*)(Qs + (w * 16 + c16) * 64 + 32 + g * 8);

  float mrow[4], lrow[4];
  for (int r = 0; r < 4; r++) { mrow[r] = -1e30f; lrow[r] = 0.f; }
  int qrow_base = qt * 64 + w * 16 + g * 4;

  // ---- pass 1: online softmax stats (m, l) ----
  for (int c = 0; c <= qt; c++) {
    uint4 t0 = *(const uint4*)(kbase + (size_t)c * 4096 + (size_t)tid * 8);
    uint4 t1 = *(const uint4*)(kbase + (size_t)c * 4096 + (size_t)(tid + 256) * 8);
    __syncthreads();
    *(uint4*)(Ks + (size_t)tid * 8) = t0;
    *(uint4*)(Ks + (size_t)(tid + 256) * 8) = t1;
    __syncthreads();
    for (int ft = 0; ft < 4; ft++) {
      v8bf b0 = *(const v8bf*)(Ks + (ft * 16 + c16) * 64 + g * 8);
      v8bf b1 = *(const v8bf*)(Ks + (ft * 16 + c16) * 64 + 32 + g * 8);
      v4f s = (v4f){0.f, 0.f, 0.f, 0.f};
      s = __builtin_amdgcn_mfma_f32_16x16x32_bf16(aq0, b0, s, 0, 0, 0);
      s = __builtin_amdgcn_mfma_f32_16x16x32_bf16(aq1, b1, s, 0, 0, 0);
      int f = c * 64 + ft * 16 + c16;
      for (int r = 0; r < 4; r++) {
        bool ok = f <= (qrow_base + r);
        float sv = ok ? s[r] * 0.125f : -1e30f;
        float tm = sv;
        for (int d2 = 1; d2 < 16; d2 <<= 1) tm = fmaxf(tm, __shfl_xor(tm, d2));
        float mn = fmaxf(mrow[r], tm);
        float e = ok ? __expf(sv - mn) : 0.f;
        float ts = e;
        for (int d2 = 1; d2 < 16; d2 <<= 1) ts += __shfl_xor(ts, d2);
        lrow[r] = lrow[r] * __expf(mrow[r] - mn) + ts;
        mrow[r] = mn;
      }
    }
  }

  float rl[4];
  for (int r = 0; r < 4; r++) rl[r] = 1.f / lrow[r];

  // ---- pass 2: recompute S, write normalized P, accumulate O = P@V ----
  v4f accO[4];
  for (int nt = 0; nt < 4; nt++) accO[nt] = (v4f){0.f, 0.f, 0.f, 0.f};

  for (int c = 0; c < 32; c++) {
    bool live = (c <= qt);   // block-uniform
    if (live) {
      uint4 t0 = *(const uint4*)(kbase + (size_t)c * 4096 + (size_t)tid * 8);
      uint4 t1 = *(const uint4*)(kbase + (size_t)c * 4096 + (size_t)(tid + 256) * 8);
      __syncthreads();
      *(uint4*)(Ks + (size_t)tid * 8) = t0;
      *(uint4*)(Ks + (size_t)(tid + 256) * 8) = t1;
      __syncthreads();
    }
    for (int fp = 0; fp < 2; fp++) {
      for (int t2 = 0; t2 < 2; t2++) {
        int ft = fp * 2 + t2;
        int f = c * 64 + ft * 16 + c16;
        float pv[4];
        if (live) {
          v8bf b0 = *(const v8bf*)(Ks + (ft * 16 + c16) * 64 + g * 8);
          v8bf b1 = *(const v8bf*)(Ks + (ft * 16 + c16) * 64 + 32 + g * 8);
          v4f s = (v4f){0.f, 0.f, 0.f, 0.f};
          s = __builtin_amdgcn_mfma_f32_16x16x32_bf16(aq0, b0, s, 0, 0, 0);
          s = __builtin_amdgcn_mfma_f32_16x16x32_bf16(aq1, b1, s, 0, 0, 0);
          for (int r = 0; r < 4; r++) {
            bool ok = f <= (qrow_base + r);
            pv[r] = ok ? __expf(s[r] * 0.125f - mrow[r]) * rl[r] : 0.f;
          }
        } else {
          for (int r = 0; r < 4; r++) pv[r] = 0.f;
        }
        for (int r = 0; r < 4; r++) {
          pbase[(size_t)(w * 16 + g * 4 + r) * 2048 + f] = pv[r];
          Pt[w][(g * 4 + r) * 32 + t2 * 16 + c16] = f2b(pv[r]);
        }
      }
      if (live) {
        v8bf pa = *(const v8bf*)(&Pt[w][c16 * 32 + g * 8]);
        for (int nt = 0; nt < 4; nt++) {
          const UST* vp = vbase + (size_t)(nt * 16 + c16) * 2048 + c * 64 + fp * 32 + g * 8;
          v8bf vb = *(const v8bf*)vp;
          accO[nt] = __builtin_amdgcn_mfma_f32_16x16x32_bf16(pa, vb, accO[nt], 0, 0, 0);
        }
      }
    }
  }

  // write O tile (bf16, (B,T,C) layout)
  for (int nt = 0; nt < 4; nt++)
    for (int r = 0; r < 4; r++) {
      int qrow = qt * 64 + w * 16 + g * 4 + r;
      int col = hn * 64 + nt * 16 + c16;
      oh[(size_t)(b * 2048 + qrow) * 1024 + col] = f2b(accO[nt][r]);
    }
}

extern "C" void kernel_launch(void* const* d_in, const int* in_sizes, int n_in,
                              void* d_out, int out_size, void* d_ws, size_t ws_size,
                              hipStream_t stream) {
  const float* x  = (const float*)d_in[0];
  const float* Wq = (const float*)d_in[1];
  const float* bq = (const float*)d_in[2];
  const float* Wk = (const float*)d_in[3];
  const float* bk = (const float*)d_in[4];
  const float* Wv = (const float*)d_in[5];
  const float* bv = (const float*)d_in[6];
  const float* Wo = (const float*)d_in[7];
  const float* bo = (const float*)d_in[8];

  float* out  = (float*)d_out;          // (B,T,C) = 8388608 floats
  float* Pout = out + 8388608;          // (B,N,T,T) = 268435456 floats

  // workspace layout (needs ~92.3 MB)
  UST* xb  = (UST*)d_ws;                // 8192x1024 bf16
  UST* wqT = xb  + 8388608;             // 1024x1024 each, transposed bf16
  UST* wkT = wqT + 1048576;
  UST* wvT = wkT + 1048576;
  UST* woT = wvT + 1048576;
  UST* qhp = woT + 1048576;             // (B,N,T,D) bf16
  UST* khp = qhp + 8388608;             // (B,N,T,D) bf16
  UST* vTp = khp + 8388608;             // (B,N,D,T) bf16
  UST* ohp = vTp + 8388608;             // (B,T,C) bf16 attention output

  k_convert<<<8192, 256, 0, stream>>>(x, xb, 8388608);
  dim3 tb(32, 8), tg(32, 32);
  k_transpose<<<tg, tb, 0, stream>>>(Wq, wqT, 1024, 1024);
  k_transpose<<<tg, tb, 0, stream>>>(Wk, wkT, 1024, 1024);
  k_transpose<<<tg, tb, 0, stream>>>(Wv, wvT, 1024, 1024);
  k_transpose<<<tg, tb, 0, stream>>>(Wo, woT, 1024, 1024);

  dim3 gg(8, 64);  // (N/128, M/128)
  k_gemm_bt<<<gg, 256, 0, stream>>>(xb, wqT, bq, 8192, 1024, 1024, 1, qhp);
  k_gemm_bt<<<gg, 256, 0, stream>>>(xb, wkT, bk, 8192, 1024, 1024, 1, khp);
  k_gemm_bt<<<gg, 256, 0, stream>>>(xb, wvT, bv, 8192, 1024, 1024, 2, vTp);

  dim3 ag(32, 16, 4);  // (qt, head, batch)
  k_attn<<<ag, 256, 0, stream>>>(qhp, khp, vTp, Pout, ohp);

  k_gemm_bt<<<gg, 256, 0, stream>>>(ohp, woT, bo, 8192, 1024, 1024, 3, d_out);
}